// Round 1
// 174.712 us; speedup vs baseline: 1.0019x; 1.0019x over previous
//
#include <hip/hip_runtime.h>
#include <hip/hip_fp16.h>
#include <stdint.h>

#define DIM 256
#define KE  768
#define NW  5376

typedef _Float16 half8 __attribute__((ext_vector_type(8)));
typedef float floatx4 __attribute__((ext_vector_type(4)));

// Workspace layout (bytes):
//   Xe    : 8192*768 ushort @ 0          (12,582,912)  [xh*64 | xh | xl*2^11]
//   We    : 5376*768 ushort @ 12582912   ( 8,257,536)  [wh*32 | wl*2^11 | wh]
//   wnorm : 5376 float      @ 20840448
//   xnorm : 8192 float      @ 20861952
//   best  : 24576 u64       @ 20894720   (level*8192+row) packed (d2<<32)|idx
#define WS_WE_OFF    12582912
#define WS_WNORM_OFF 20840448
#define WS_XNORM_OFF 20861952
#define WS_BEST_OFF  20894720

// One wave per row: fp32 norm + fp16 hi/lo split into the expanded layouts.
// Segment pairing in the GEMM: (xh*64)*(wh*32) = 2^11*xh*wh ; xh*(wl*2^11) ;
// (xl*2^11)*wh  => acc = 2^11 * (xh*wh + xh*wl + xl*wh), no mid-loop rescale.
// Power-of-2 scales are exact in fp16 => bit-identical accumulation vs the
// previous (absmax 0.0) kernel.
__global__ __launch_bounds__(256) void conv_kernel(
    const float* __restrict__ x, const float* __restrict__ w1,
    const float* __restrict__ w2, const float* __restrict__ w3,
    ushort* __restrict__ Xe, ushort* __restrict__ We,
    float* __restrict__ wnorm, float* __restrict__ xnorm) {
  int task = blockIdx.x * 4 + (threadIdx.x >> 6);
  int lane = threadIdx.x & 63;
  const float* src; ushort* dst; float* ndst; int isx;
  if (task < 8192) {
    src = x + (size_t)task * DIM; dst = Xe + (size_t)task * KE;
    ndst = xnorm + task; isx = 1;
  } else {
    int wi = task - 8192;
    if (wi < 256)       src = w1 + (size_t)wi * DIM;
    else if (wi < 1280) src = w2 + (size_t)(wi - 256) * DIM;
    else                src = w3 + (size_t)(wi - 1280) * DIM;
    dst = We + (size_t)wi * KE; ndst = wnorm + wi; isx = 0;
  }
  float4 v = *(const float4*)(src + lane * 4);
  float fv[4] = {v.x, v.y, v.z, v.w};
  float s = fv[0]*fv[0] + fv[1]*fv[1] + fv[2]*fv[2] + fv[3]*fv[3];
  #pragma unroll
  for (int o = 32; o > 0; o >>= 1) s += __shfl_xor(s, o);
  if (lane == 0) *ndst = s;

  float scale = isx ? 64.0f : 32.0f;
  ushort h[4], hs[4], l[4];
  #pragma unroll
  for (int e = 0; e < 4; ++e) {
    __half hh = __float2half(fv[e]);
    float hf = __half2float(hh);
    h[e]  = __half_as_ushort(hh);
    hs[e] = __half_as_ushort(__float2half(hf * scale));       // exact (pow2)
    l[e]  = __half_as_ushort(__float2half((fv[e] - hf) * 2048.0f));
  }
  ushort4 h4 = make_ushort4(h[0], h[1], h[2], h[3]);
  ushort4 s4 = make_ushort4(hs[0], hs[1], hs[2], hs[3]);
  ushort4 l4 = make_ushort4(l[0], l[1], l[2], l[3]);
  if (isx) {  // [xh*64 | xh | xl2]
    *(ushort4*)(dst + lane * 4)        = s4;
    *(ushort4*)(dst + 256 + lane * 4)  = h4;
    *(ushort4*)(dst + 512 + lane * 4)  = l4;
  } else {    // [wh*32 | wl2 | wh]
    *(ushort4*)(dst + lane * 4)        = s4;
    *(ushort4*)(dst + 256 + lane * 4)  = l4;
    *(ushort4*)(dst + 512 + lane * 4)  = h4;
  }
}

// 256x256-tile, 8-wave (2Mx4N), 8-phase-style pipelined MFMA GEMM over K=768
// with fused per-row argmin.
// LDS: per operand a 4-slot ring of K-half (32-element) slabs (256 rows x 32),
// staged via global_load_lds with pre-swizzled source; steady-state
// s_waitcnt vmcnt(4) (2 half-tiles in flight), never 0 in the main loop.
// grid.x = 32 row-blocks, grid.y = 21 col-blocks (1 | 4 | 16 per level).
__global__ __launch_bounds__(512, 2) void gemm_kernel(
    const ushort* __restrict__ Xe, const ushort* __restrict__ We,
    const float* __restrict__ xnorm, const float* __restrict__ wnorm,
    unsigned long long* __restrict__ best) {
  // A ring: bytes [0, 65536)  = 4 slots x 16 KB (256 rows x 32 halves)
  // B ring: bytes [65536, 131072)
  __shared__ __align__(16) ushort AB[65536];
  __shared__ unsigned long long red[4][256];

  const int t = threadIdx.x;
  const int w = t >> 6;
  const int lane = t & 63;
  const int ln = lane & 15, q = lane >> 4;
  const int wr = w >> 2, wc = w & 3;          // 2 x 4 wave grid
  const int r0 = blockIdx.x * 256;
  const int cb = blockIdx.y;
  const int n0 = cb << 8;
  int level, lbase;
  if (cb < 1)      { level = 0; lbase = 0; }
  else if (cb < 5) { level = 1; lbase = 256; }
  else             { level = 2; lbase = 1280; }

  // Fragment LDS byte offsets. Row r, K-quarter q -> chunk (q ^ ((r>>1)&3)),
  // conflict-free ds_read_b128 (pairs of rows share a chunk = free 2-way).
  int aoff[2][4], boff[4];
  #pragma unroll
  for (int mh = 0; mh < 2; ++mh)
    #pragma unroll
    for (int mt = 0; mt < 4; ++mt) {
      int ra = wr * 128 + mh * 64 + mt * 16 + ln;
      aoff[mh][mt] = ra * 64 + ((q ^ ((ra >> 1) & 3)) << 4);
    }
  #pragma unroll
  for (int nt = 0; nt < 4; ++nt) {
    int rb = wc * 64 + nt * 16 + ln;
    boff[nt] = 65536 + rb * 64 + ((q ^ ((rb >> 1) & 3)) << 4);
  }
  const char* ABb = (const char*)AB;

  // Staging: one K-half slab = 256 rows x 4 chunks = 1024 chunks; wave w,
  // round j covers rows [w*16 + j*128, +16). LDS dest linear, global source
  // pre-swizzled with the same XOR -> involution.
  const int sr = (w << 4) + (lane >> 2);
  const int sc = lane & 3;
  const int sg = sc ^ ((sr >> 1) & 3);        // same for sr and sr+128
  const ushort* srcA0 = Xe + (size_t)(r0 + sr) * KE + sg * 8;
  const ushort* srcB0 = We + (size_t)(n0 + sr) * KE + sg * 8;
  const int ldsO0 = w << 9;                   // halves: w*64 chunks
  const int ldsO1 = 4096 + (w << 9);          // +512 chunks (rows +128)

#define STAGE_A(hs_) do { const int sl_ = ((hs_) & 3) << 13; \
    __builtin_amdgcn_global_load_lds( \
        (const __attribute__((address_space(1))) void*)(srcA0 + (hs_) * 32), \
        (__attribute__((address_space(3))) void*)(AB + sl_ + ldsO0), 16, 0, 0); \
    __builtin_amdgcn_global_load_lds( \
        (const __attribute__((address_space(1))) void*)(srcA0 + 128 * KE + (hs_) * 32), \
        (__attribute__((address_space(3))) void*)(AB + sl_ + ldsO1), 16, 0, 0); \
  } while (0)
#define STAGE_B(hs_) do { const int sl_ = 32768 + (((hs_) & 3) << 13); \
    __builtin_amdgcn_global_load_lds( \
        (const __attribute__((address_space(1))) void*)(srcB0 + (hs_) * 32), \
        (__attribute__((address_space(3))) void*)(AB + sl_ + ldsO0), 16, 0, 0); \
    __builtin_amdgcn_global_load_lds( \
        (const __attribute__((address_space(1))) void*)(srcB0 + 128 * KE + (hs_) * 32), \
        (__attribute__((address_space(3))) void*)(AB + sl_ + ldsO1), 16, 0, 0); \
  } while (0)

  floatx4 acc[8][4];
  #pragma unroll
  for (int i = 0; i < 8; ++i)
    #pragma unroll
    for (int j = 0; j < 4; ++j) acc[i][j] = (floatx4)0.0f;

  half8 av[4], bv[4];

  // Prologue: stage K-halves 0,1 of A and B (8 loads/thread); need halves 0
  // complete -> allow newest 4 (A1,B1) outstanding.
  STAGE_A(0); STAGE_B(0); STAGE_A(1); STAGE_B(1);
  asm volatile("s_waitcnt vmcnt(4)" ::: "memory");
  __builtin_amdgcn_s_barrier();
  __builtin_amdgcn_sched_barrier(0);

  // Phase pair per K-half h: PH0 computes m-tiles 0..3, PH1 m-tiles 4..7.
  // Stage A(h+2) in PH0, B(h+2) in PH1; end-of-pair vmcnt(4) retires the
  // (oldest) A(h+1),B(h+1) so the next pair's ds_reads are safe after the
  // barrier. Ring distance 2 guarantees no read/write slot overlap.
#define PH0(h_, STG_) { \
    const int sb_ = ((h_) & 3) << 14; \
    _Pragma("unroll") for (int mt = 0; mt < 4; ++mt) \
      av[mt] = *(const half8*)(ABb + sb_ + aoff[0][mt]); \
    _Pragma("unroll") for (int nt = 0; nt < 4; ++nt) \
      bv[nt] = *(const half8*)(ABb + sb_ + boff[nt]); \
    if (STG_) STAGE_A((h_) + 2); \
    __builtin_amdgcn_sched_barrier(0); \
    __builtin_amdgcn_s_barrier(); \
    __builtin_amdgcn_sched_barrier(0); \
    __builtin_amdgcn_s_setprio(1); \
    _Pragma("unroll") for (int mt = 0; mt < 4; ++mt) \
      _Pragma("unroll") for (int nt = 0; nt < 4; ++nt) \
        acc[mt][nt] = __builtin_amdgcn_mfma_f32_16x16x32_f16( \
            av[mt], bv[nt], acc[mt][nt], 0, 0, 0); \
    __builtin_amdgcn_s_setprio(0); \
    __builtin_amdgcn_sched_barrier(0); \
    __builtin_amdgcn_s_barrier(); \
    __builtin_amdgcn_sched_barrier(0); \
  }
#define PH1(h_, STG_, VMS_) { \
    const int sb_ = ((h_) & 3) << 14; \
    _Pragma("unroll") for (int mt = 0; mt < 4; ++mt) \
      av[mt] = *(const half8*)(ABb + sb_ + aoff[1][mt]); \
    if (STG_) STAGE_B((h_) + 2); \
    __builtin_amdgcn_sched_barrier(0); \
    __builtin_amdgcn_s_barrier(); \
    __builtin_amdgcn_sched_barrier(0); \
    __builtin_amdgcn_s_setprio(1); \
    _Pragma("unroll") for (int mt = 0; mt < 4; ++mt) \
      _Pragma("unroll") for (int nt = 0; nt < 4; ++nt) \
        acc[4 + mt][nt] = __builtin_amdgcn_mfma_f32_16x16x32_f16( \
            av[mt], bv[nt], acc[4 + mt][nt], 0, 0, 0); \
    __builtin_amdgcn_s_setprio(0); \
    VMS_; \
    __builtin_amdgcn_sched_barrier(0); \
    __builtin_amdgcn_s_barrier(); \
    __builtin_amdgcn_sched_barrier(0); \
  }

  #pragma unroll 1
  for (int h = 0; h < 22; ++h) {
    PH0(h, 1);
    PH1(h, 1, asm volatile("s_waitcnt vmcnt(4)" ::: "memory"));
  }
  // Tail: K-halves 22,23 (no more staging; drain before the last pair).
  PH0(22, 0);
  PH1(22, 0, asm volatile("s_waitcnt vmcnt(0)" ::: "memory"));
  PH0(23, 0);
  PH1(23, 0, );

  // acc = 2^11 * dot. d2 = xn + wn - 2*dot = xn + wn - acc * 2^-10.
  float wnv[4];
  #pragma unroll
  for (int nt = 0; nt < 4; ++nt) wnv[nt] = wnorm[n0 + wc * 64 + nt * 16 + ln];

  #pragma unroll
  for (int mtg = 0; mtg < 8; ++mtg) {
    #pragma unroll
    for (int r = 0; r < 4; ++r) {
      int rowl = wr * 128 + mtg * 16 + q * 4 + r;
      float xnv = xnorm[r0 + rowl];
      unsigned long long bp = ~0ull;
      #pragma unroll
      for (int nt = 0; nt < 4; ++nt) {
        float d2 = fmaxf(xnv + wnv[nt] - acc[mtg][nt][r] * 0.0009765625f, 0.0f);
        unsigned col = (unsigned)(n0 + wc * 64 + nt * 16 + ln - lbase);
        unsigned long long p =
            ((unsigned long long)__float_as_uint(d2) << 32) | col;
        bp = (p < bp) ? p : bp;
      }
      #pragma unroll
      for (int off = 1; off < 16; off <<= 1) {
        unsigned long long o = __shfl_xor(bp, off);
        bp = (o < bp) ? o : bp;
      }
      if (ln == 0) red[wc][rowl] = bp;
    }
  }
  __syncthreads();
  if (t < 256) {
    unsigned long long m0 = red[0][t], m1 = red[1][t];
    unsigned long long m2 = red[2][t], m3 = red[3][t];
    unsigned long long m = m0 < m1 ? m0 : m1;
    if (m2 < m) m = m2;
    if (m3 < m) m = m3;
    atomicMin(&best[level * 8192 + r0 + t], m);
  }
}

// One wave per (level,row): coords + exact fp32 quantization error.
__global__ __launch_bounds__(256) void finalize_kernel(
    const float* __restrict__ x, const float* __restrict__ w1,
    const float* __restrict__ w2, const float* __restrict__ w3,
    const unsigned long long* __restrict__ best, float* __restrict__ out) {
  int task = blockIdx.x * 4 + (threadIdx.x >> 6);
  int lane = threadIdx.x & 63;
  int level = task >> 13;
  int row = task & 8191;
  const float* w; unsigned side;
  if (level == 0)      { w = w1; side = 16; }
  else if (level == 1) { w = w2; side = 32; }
  else                 { w = w3; side = 64; }
  unsigned idx = (unsigned)(best[level * 8192 + row] & 0xFFFFFFFFull);
  float4 xv = *(const float4*)(x + (size_t)row * DIM + lane * 4);
  float4 wv = *(const float4*)(w + (size_t)idx * DIM + lane * 4);
  float dx = xv.x - wv.x, dy = xv.y - wv.y, dz = xv.z - wv.z, dw = xv.w - wv.w;
  float s = dx * dx + dy * dy + dz * dz + dw * dw;
  #pragma unroll
  for (int o = 32; o > 0; o >>= 1) s += __shfl_xor(s, o);
  if (lane == 0) {
    out[level * 16384 + row * 2 + 0] = (float)(idx / side);
    out[level * 16384 + row * 2 + 1] = (float)(idx % side);
    out[49152 + level * 8192 + row] = sqrtf(s);
  }
}

extern "C" void kernel_launch(void* const* d_in, const int* in_sizes, int n_in,
                              void* d_out, int out_size, void* d_ws, size_t ws_size,
                              hipStream_t stream) {
  const float* x  = (const float*)d_in[0];
  const float* w1 = (const float*)d_in[1];
  const float* w2 = (const float*)d_in[2];
  const float* w3 = (const float*)d_in[3];
  ushort* Xe = (ushort*)d_ws;
  ushort* We = (ushort*)((char*)d_ws + WS_WE_OFF);
  float* wnorm = (float*)((char*)d_ws + WS_WNORM_OFF);
  float* xnorm = (float*)((char*)d_ws + WS_XNORM_OFF);
  unsigned long long* best = (unsigned long long*)((char*)d_ws + WS_BEST_OFF);

  hipMemsetAsync(best, 0xFF, 24576 * sizeof(unsigned long long), stream);
  conv_kernel<<<3392, 256, 0, stream>>>(x, w1, w2, w3, Xe, We, wnorm, xnorm);
  gemm_kernel<<<dim3(32, 21), 512, 0, stream>>>(Xe, We, xnorm, wnorm, best);
  finalize_kernel<<<6144, 256, 0, stream>>>(x, w1, w2, w3, best, (float*)d_out);
}